// Round 1
// baseline (458.137 us; speedup 1.0000x reference)
//
#include <hip/hip_runtime.h>
#include <cstdint>

// SREChead: stem 1x1 (128->64) + 2x 3x3 (64->64), each BN+SiLU, then 1x1
// reg(4)/obj(1) heads + YOLOX decode. B=64, 80x80, stride 32.
// R7: conv staging rebuilt as single-phase global_load_lds DMA (width 16):
// full 6x82x64ci tile staged once (8 granules x 512 slots x 16B, +16us
// granule pad for bank rotation), OOB lanes redirected to a 16B zero page.
// 1 barrier/block instead of 4; no VGPR round-trip / ds_write in staging.
// LDS 65.8KB -> 2 blocks/CU (was 3) -- traded for DMA + single drain.

typedef short short8 __attribute__((ext_vector_type(8)));
typedef float floatx4 __attribute__((ext_vector_type(4)));
typedef float fx4 __attribute__((ext_vector_type(4)));
typedef unsigned short us4 __attribute__((ext_vector_type(4)));

#define NPIX 6400
#define SEGP 4112    // conv granule stride (ushort): 512 slots * 8 + 16 pad
                     // byte stride 8224 -> word stride %32 == 8 (quad rotation)
#define CGS2 2576    // head h-tile granule stride: 322 px * 8 us (320 used)

static __device__ __forceinline__ unsigned short f2bf(float f) {
    unsigned u = __builtin_bit_cast(unsigned, f);
    u += 0x7fffu + ((u >> 16) & 1u);      // round-to-nearest-even
    return (unsigned short)(u >> 16);
}

static __device__ __forceinline__ float silu_(float v) {
    return v / (1.0f + __expf(-v));
}

static __device__ __forceinline__ void gload_lds16(const void* g, void* l) {
    __builtin_amdgcn_global_load_lds(
        (const __attribute__((address_space(1))) unsigned int*)g,
        (__attribute__((address_space(3))) unsigned int*)l, 16, 0, 0);
}

// ---------------------------------------------------------------------------
// Rearrange weights to bf16 MFMA A-frag order; also zero the 16B zero page.
//  wS  [kb(4)][ct(4)][lane][8]  from stem_w [64co][128ci]      (8192 el)
//  wB1 [kb(18)][ct(4)][lane][8] from c1_w [64co][64ci][3][3]   (36864 el)
//  wB2 same from c2_w
// co = ct*16+(lane&15); k = kb*32+(lane>>4)*8+j; conv: ci=k&63, tap=k>>6.
__global__ __launch_bounds__(256) void rearr_w_kernel(
    const float* __restrict__ ws_, const float* __restrict__ w1,
    const float* __restrict__ w2,
    unsigned short* __restrict__ wS, unsigned short* __restrict__ wB1,
    unsigned short* __restrict__ wB2, unsigned short* __restrict__ zb) {
    if (blockIdx.x == 0 && threadIdx.x < 16) zb[threadIdx.x] = 0;
    int idx = blockIdx.x * 256 + threadIdx.x;          // 0..81919
    if (idx < 8192) {
        int e = idx;
        int j = e & 7, lane = (e >> 3) & 63, ct = (e >> 9) & 3, kb = e >> 11;
        int co = ct * 16 + (lane & 15);
        int ci = kb * 32 + ((lane >> 4) * 8) + j;
        wS[e] = f2bf(ws_[co * 128 + ci]);
        return;
    }
    idx -= 8192;
    const float* src = (idx < 36864) ? w1 : w2;
    unsigned short* dst = (idx < 36864) ? wB1 : wB2;
    int e = (idx < 36864) ? idx : idx - 36864;
    int j = e & 7, lane = (e >> 3) & 63, ct = (e >> 9) & 3, kb = e >> 11;
    int co = ct * 16 + (lane & 15);
    int k = kb * 32 + ((lane >> 4) * 8) + j;
    int ci = k & 63, tap = k >> 6;
    dst[e] = f2bf(src[(co * 64 + ci) * 9 + tap]);
}

// ---------------------------------------------------------------------------
// Stem: f1[b][p][co] = silu(bn(sum_ci x[b][ci][p] * W[co][ci]))  (NHWC bf16)
// Block: 128-px tile. Two phases of 64 ci: stage fp32 rows [64][129] (33 KB,
// padded -> conflict-free), frag-build transposes via 8x ds_read_b32 + pack.
__global__ __launch_bounds__(256) void stem_kernel(
    const float* __restrict__ x, const unsigned short* __restrict__ wS,
    const float* __restrict__ scale, const float* __restrict__ shift,
    unsigned short* __restrict__ f1) {
    __shared__ __align__(16) float xs[64 * 129];   // 33024 B
    int b = blockIdx.y;
    int tid = threadIdx.x;
    int pbase = blockIdx.x * 128;
    int lane = tid & 63, wv = tid >> 6;
    int l15 = lane & 15, q = lane >> 4;

    float sc[4][4], sh[4][4];
    #pragma unroll
    for (int ct = 0; ct < 4; ++ct)
        #pragma unroll
        for (int r = 0; r < 4; ++r) {
            sc[ct][r] = scale[ct * 16 + q * 4 + r];
            sh[ct][r] = shift[ct * 16 + q * 4 + r];
        }

    floatx4 acc[4][2];   // [ct][t]
    floatx4 zf = {0.0f, 0.0f, 0.0f, 0.0f};
    #pragma unroll
    for (int ct = 0; ct < 4; ++ct)
        #pragma unroll
        for (int t = 0; t < 2; ++t) acc[ct][t] = zf;

    #pragma unroll
    for (int p = 0; p < 2; ++p) {
        if (p) __syncthreads();        // WAR: phase-0 frag reads done
        // stage 64 ci rows x 128 px fp32: 2048 16B chunks, 8/thread, coalesced
        #pragma unroll
        for (int i = 0; i < 8; ++i) {
            int c = i * 256 + tid;
            int row = c >> 5, seg = c & 31;
            fx4 v = *(const fx4*)(
                x + ((size_t)(b * 128 + p * 64 + row)) * NPIX + pbase + seg * 4);
            *(fx4*)(xs + row * 129 + seg * 4) = v;
        }
        __syncthreads();

        #pragma unroll
        for (int kk = 0; kk < 2; ++kk) {
            int kb = p * 2 + kk;
            short8 wf[4];
            #pragma unroll
            for (int ct = 0; ct < 4; ++ct)
                wf[ct] = *(const short8*)(wS + ((kb * 4 + ct) * 64 + lane) * 8);
            short8 xf[2];
            #pragma unroll
            for (int t = 0; t < 2; ++t) {
                int px = (wv * 2 + t) * 16 + l15;
                const float* src = xs + (kk * 32 + q * 8) * 129 + px;
                unsigned short tmp[8];
                #pragma unroll
                for (int j = 0; j < 8; ++j) tmp[j] = f2bf(src[j * 129]);
                xf[t] = *(const short8*)tmp;
            }
            #pragma unroll
            for (int ct = 0; ct < 4; ++ct)
                #pragma unroll
                for (int t = 0; t < 2; ++t)
                    acc[ct][t] = __builtin_amdgcn_mfma_f32_16x16x32_bf16(
                        wf[ct], xf[t], acc[ct][t], 0, 0, 0);
        }
    }

    #pragma unroll
    for (int t = 0; t < 2; ++t) {
        int pg = pbase + (wv * 2 + t) * 16 + l15;
        unsigned short* dst = f1 + ((size_t)b * NPIX + pg) * 64;
        #pragma unroll
        for (int ct = 0; ct < 4; ++ct) {
            us4 v;
            #pragma unroll
            for (int r = 0; r < 4; ++r)
                v[r] = f2bf(silu_(acc[ct][t][r] * sc[ct][r] + sh[ct][r]));
            *(us4*)(dst + ct * 16 + q * 4) = v;
        }
    }
}

// ---------------------------------------------------------------------------
// Conv core, 4-ct N-blocking: wave wv owns output row y0+wv, all 64 co,
// 5 col-tiles. Full 64-ci tile staged ONCE via global_load_lds DMA:
// 8 granules (ci 8-chunks) x 512 px-slots x 16B; wave-uniform LDS dest =
// granule base + pixB*16, per-lane global src (OOB/pad lanes -> zero page).
// One barrier, then 9 taps x 2 K-halves x 5 pt x 4 ct = 360 MFMA.
static __device__ __forceinline__ void conv_core(
    const unsigned short* __restrict__ fin, const unsigned short* __restrict__ wB,
    const unsigned short* __restrict__ zbuf,
    unsigned short* tile, floatx4 (*acc)[5], int b, int y0,
    int tid, int lane, int wv, int l15, int q) {
    const unsigned short* fb = fin + (size_t)b * NPIX * 64;
    floatx4 zf = {0.0f, 0.0f, 0.0f, 0.0f};
    #pragma unroll
    for (int c4 = 0; c4 < 4; ++c4)
        #pragma unroll
        for (int pt = 0; pt < 5; ++pt) acc[c4][pt] = zf;

    // stage: 4096 chunks of 16B, 16 DMA issues/thread, no VGPR round-trip
    #pragma unroll
    for (int i = 0; i < 16; ++i) {
        int cbase = i * 256 + wv * 64;     // wave-uniform chunk base
        int g = cbase >> 9;                // granule 0..7 (ci = g*8..g*8+7)
        int pixB = cbase & 511;            // wave-uniform slot base
        int pixL = pixB + lane;
        int r = (pixL * 25) >> 11;         // == pixL/82 for 0..511
        int c = pixL - r * 82;
        int gy = y0 - 1 + r, gx = c - 1;
        const unsigned short* src =
            (pixL < 492 && (unsigned)gy < 80u && (unsigned)gx < 80u)
                ? fb + (size_t)(gy * 80 + gx) * 64 + g * 8
                : zbuf;
        gload_lds16(src, tile + (size_t)g * SEGP + (size_t)pixB * 8);
    }
    __syncthreads();   // drains vmcnt(0): DMA landed

    #pragma unroll
    for (int trow = 0; trow < 3; ++trow) {
        const int dy = trow - 1;
        #pragma unroll
        for (int tc = 0; tc < 3; ++tc) {
            const int dx = tc - 1;
            #pragma unroll
            for (int half = 0; half < 2; ++half) {
                const int kb = (trow * 3 + tc) * 2 + half;
                short8 w4[4];
                #pragma unroll
                for (int c4 = 0; c4 < 4; ++c4)
                    w4[c4] = *(const short8*)(wB + ((kb * 4 + c4) * 64 + lane) * 8);
                #pragma unroll
                for (int pt = 0; pt < 5; ++pt) {
                    int pix = (wv + 1 + dy) * 82 + pt * 16 + l15 + 1 + dx;
                    short8 b8 = *(const short8*)(
                        tile + (size_t)(half * 4 + q) * SEGP + pix * 8);
                    #pragma unroll
                    for (int c4 = 0; c4 < 4; ++c4)
                        acc[c4][pt] = __builtin_amdgcn_mfma_f32_16x16x32_bf16(
                            w4[c4], b8, acc[c4][pt], 0, 0, 0);
                }
            }
        }
    }
}

// ---------------------------------------------------------------------------
__global__ __launch_bounds__(256, 2) void conv3_kernel(
    const unsigned short* __restrict__ fin, const unsigned short* __restrict__ wB,
    const unsigned short* __restrict__ zbuf,
    const float* __restrict__ scale, const float* __restrict__ shift,
    unsigned short* __restrict__ fout) {
    __shared__ __align__(16) unsigned short tile[8 * SEGP];  // 65792 B
    int b = blockIdx.y, y0 = blockIdx.x * 4;
    int tid = threadIdx.x;
    int lane = tid & 63, wv = tid >> 6;
    int l15 = lane & 15, q = lane >> 4;

    floatx4 acc[4][5];
    conv_core(fin, wB, zbuf, tile, acc, b, y0, tid, lane, wv, l15, q);

    float sc4[4][4], sh4[4][4];
    #pragma unroll
    for (int c4 = 0; c4 < 4; ++c4)
        #pragma unroll
        for (int r = 0; r < 4; ++r) {
            sc4[c4][r] = scale[c4 * 16 + q * 4 + r];
            sh4[c4][r] = shift[c4 * 16 + q * 4 + r];
        }
    #pragma unroll
    for (int pt = 0; pt < 5; ++pt) {
        int pg = (y0 + wv) * 80 + pt * 16 + l15;
        unsigned short* dst = fout + ((size_t)b * NPIX + pg) * 64;
        #pragma unroll
        for (int c4 = 0; c4 < 4; ++c4) {
            us4 v;
            #pragma unroll
            for (int r = 0; r < 4; ++r)
                v[r] = f2bf(silu_(acc[c4][pt][r] * sc4[c4][r] + sh4[c4][r]));
            *(us4*)(dst + c4 * 16 + q * 4) = v;
        }
    }
}

// ---------------------------------------------------------------------------
__global__ __launch_bounds__(256, 2) void conv_head_kernel(
    const unsigned short* __restrict__ fin, const unsigned short* __restrict__ wB,
    const unsigned short* __restrict__ zbuf,
    const float* __restrict__ scale, const float* __restrict__ shift,
    const float* __restrict__ reg_w, const float* __restrict__ reg_b,
    const float* __restrict__ obj_w, const float* __restrict__ obj_b,
    float* __restrict__ out) {
    __shared__ __align__(16) unsigned short tile[8 * SEGP];  // 65792 B
    int b = blockIdx.y, y0 = blockIdx.x * 4;
    int tid = threadIdx.x;
    int lane = tid & 63, wv = tid >> 6;
    int l15 = lane & 15, q = lane >> 4;

    floatx4 acc[4][5];
    conv_core(fin, wB, zbuf, tile, acc, b, y0, tid, lane, wv, l15, q);

    __syncthreads();   // conv reads done -> reuse LDS for h (granule stride CGS2)

    // BN+SiLU -> h[granule co>>3][pix 0..319] (stride CGS2, conflict-free)
    float sc4[4][4], sh4[4][4];
    #pragma unroll
    for (int c4 = 0; c4 < 4; ++c4)
        #pragma unroll
        for (int r = 0; r < 4; ++r) {
            sc4[c4][r] = scale[c4 * 16 + q * 4 + r];
            sh4[c4][r] = shift[c4 * 16 + q * 4 + r];
        }
    #pragma unroll
    for (int pt = 0; pt < 5; ++pt) {
        int pix = wv * 80 + pt * 16 + l15;   // block-local pixel 0..319
        #pragma unroll
        for (int c4 = 0; c4 < 4; ++c4) {
            int gco = c4 * 2 + (q >> 1);     // co>>3
            us4 v;
            #pragma unroll
            for (int r = 0; r < 4; ++r)
                v[r] = f2bf(silu_(acc[c4][pt][r] * sc4[c4][r] + sh4[c4][r]));
            *(us4*)(tile + gco * CGS2 + pix * 8 + (q & 1) * 4) = v;
        }
    }

    // head B-frags: B[k=co][n] = reg_w[n][co] (n<4), obj_w[co] (n==4), else 0
    short8 hbf[2];
    #pragma unroll
    for (int kb2 = 0; kb2 < 2; ++kb2) {
        int k0 = kb2 * 32 + q * 8;
        short8 f = {};
        if (l15 < 4) {
            #pragma unroll
            for (int j = 0; j < 8; ++j) f[j] = (short)f2bf(reg_w[l15 * 64 + k0 + j]);
        } else if (l15 == 4) {
            #pragma unroll
            for (int j = 0; j < 8; ++j) f[j] = (short)f2bf(obj_w[k0 + j]);
        }
        hbf[kb2] = f;
    }

    __syncthreads();

    floatx4 zf = {0.0f, 0.0f, 0.0f, 0.0f};
    floatx4 acc5[5];
    #pragma unroll
    for (int t = 0; t < 5; ++t) acc5[t] = zf;
    #pragma unroll
    for (int t = 0; t < 5; ++t) {
        int mt = wv * 5 + t;
        int pix = mt * 16 + l15;
        #pragma unroll
        for (int kb2 = 0; kb2 < 2; ++kb2) {
            short8 a = *(const short8*)(tile + (kb2 * 4 + q) * CGS2 + pix * 8);
            acc5[t] = __builtin_amdgcn_mfma_f32_16x16x32_bf16(
                a, hbf[kb2], acc5[t], 0, 0, 0);
        }
    }

    float bias = 0.0f;
    if (l15 < 4) bias = reg_b[l15];
    else if (l15 == 4) bias = obj_b[0];

    #pragma unroll
    for (int t = 0; t < 5; ++t) {
        int mt = wv * 5 + t;
        #pragma unroll
        for (int r = 0; r < 4; ++r) {
            int pixL = mt * 16 + q * 4 + r;
            if (l15 < 5) {
                float v = acc5[t][r] + bias;
                float gx = (float)(pixL % 80);
                float gy = (float)(y0 + pixL / 80);
                float o;
                if (l15 == 0)      o = (v + gx) * 32.0f;
                else if (l15 == 1) o = (v + gy) * 32.0f;
                else if (l15 < 4)  o = __expf(v) * 32.0f;
                else               o = 1.0f / (1.0f + __expf(-v));
                out[((size_t)b * NPIX + y0 * 80 + pixL) * 5 + l15] = o;
            }
        }
    }
}

// ---------------------------------------------------------------------------
extern "C" void kernel_launch(void* const* d_in, const int* in_sizes, int n_in,
                              void* d_out, int out_size, void* d_ws, size_t ws_size,
                              hipStream_t stream) {
    const float* x          = (const float*)d_in[0];
    const float* stem_w     = (const float*)d_in[1];
    const float* stem_scale = (const float*)d_in[2];
    const float* stem_shift = (const float*)d_in[3];
    const float* c1_w       = (const float*)d_in[4];
    const float* c1_scale   = (const float*)d_in[5];
    const float* c1_shift   = (const float*)d_in[6];
    const float* c2_w       = (const float*)d_in[7];
    const float* c2_scale   = (const float*)d_in[8];
    const float* c2_shift   = (const float*)d_in[9];
    const float* reg_w      = (const float*)d_in[10];
    const float* reg_b      = (const float*)d_in[11];
    const float* obj_w      = (const float*)d_in[12];
    const float* obj_b      = (const float*)d_in[13];
    float* out = (float*)d_out;

    // ws (ushort units): wS[8192] | wB1[36864] | wB2[36864] | f1 | f2 | zb[16]
    const size_t needed =
        ((size_t)8192 + 73728 + 2 * (size_t)64 * NPIX * 64 + 16) * 2;
    if (ws_size < needed) return;

    unsigned short* ws  = (unsigned short*)d_ws;
    unsigned short* wS  = ws;
    unsigned short* wB1 = ws + 8192;
    unsigned short* wB2 = wB1 + 36864;
    unsigned short* f1  = wB2 + 36864;
    unsigned short* f2  = f1 + (size_t)64 * NPIX * 64;
    unsigned short* zb  = f2 + (size_t)64 * NPIX * 64;

    rearr_w_kernel<<<320, 256, 0, stream>>>(stem_w, c1_w, c2_w, wS, wB1, wB2, zb);
    stem_kernel<<<dim3(50, 64), 256, 0, stream>>>(x, wS, stem_scale, stem_shift, f1);
    conv3_kernel<<<dim3(20, 64), 256, 0, stream>>>(f1, wB1, zb, c1_scale, c1_shift, f2);
    conv_head_kernel<<<dim3(20, 64), 256, 0, stream>>>(f2, wB2, zb, c2_scale, c2_shift,
                                                       reg_w, reg_b, obj_w, obj_b, out);
}

// Round 2
// 441.675 us; speedup vs baseline: 1.0373x; 1.0373x over previous
//
#include <hip/hip_runtime.h>
#include <cstdint>

// SREChead: stem 1x1 (128->64) + 2x 3x3 (64->64), each BN+SiLU, then 1x1
// reg(4)/obj(1) heads + YOLOX decode. B=64, 80x80, stride 32.
// R8: conv reverted to R6 (4-ct N-blocking, ci-half staging, 3 blocks/CU --
// R7's DMA+2-block variant regressed 443->458). Stem rewritten LDS-free:
// fragments built directly from global (8x coalesced dword per frag, x
// elements have zero reuse so LDS bought nothing), no barriers. All bf16
// conversions via v_cvt_pk_bf16_f32 (1 instr / 2 floats, RTNE) instead of
// the 5-op manual hack (conv3 epilogue alone had 80 f2bf/thread).

typedef short short8 __attribute__((ext_vector_type(8)));
typedef float floatx4 __attribute__((ext_vector_type(4)));
typedef float fx4 __attribute__((ext_vector_type(4)));
typedef unsigned short us4 __attribute__((ext_vector_type(4)));
typedef unsigned uint4v __attribute__((ext_vector_type(4)));
typedef unsigned uint2v __attribute__((ext_vector_type(2)));

#define NPIX 6400
#define CGS  3952    // conv tile granule stride: 494 px * 8 us (6x82=492 used)
#define CGS2 2576    // h-tile granule stride: 322 px * 8 us (320 used)

static __device__ __forceinline__ unsigned short f2bf(float f) {
    unsigned u = __builtin_bit_cast(unsigned, f);
    u += 0x7fffu + ((u >> 16) & 1u);      // round-to-nearest-even
    return (unsigned short)(u >> 16);
}

// packed bf16 convert: lo16 = bf16(a), hi16 = bf16(b); RTNE
static __device__ __forceinline__ unsigned cvt_pk_bf16(float a, float b) {
    unsigned r;
    asm("v_cvt_pk_bf16_f32 %0, %1, %2" : "=v"(r) : "v"(a), "v"(b));
    return r;
}

static __device__ __forceinline__ float silu_(float v) {
    return v / (1.0f + __expf(-v));
}

// ---------------------------------------------------------------------------
// Rearrange weights to bf16 MFMA A-frag order.
//  wS  [kb(4)][ct(4)][lane][8]  from stem_w [64co][128ci]      (8192 el)
//  wB1 [kb(18)][ct(4)][lane][8] from c1_w [64co][64ci][3][3]   (36864 el)
//  wB2 same from c2_w
// co = ct*16+(lane&15); k = kb*32+(lane>>4)*8+j; conv: ci=k&63, tap=k>>6.
__global__ __launch_bounds__(256) void rearr_w_kernel(
    const float* __restrict__ ws_, const float* __restrict__ w1,
    const float* __restrict__ w2,
    unsigned short* __restrict__ wS, unsigned short* __restrict__ wB1,
    unsigned short* __restrict__ wB2) {
    int idx = blockIdx.x * 256 + threadIdx.x;          // 0..81919
    if (idx < 8192) {
        int e = idx;
        int j = e & 7, lane = (e >> 3) & 63, ct = (e >> 9) & 3, kb = e >> 11;
        int co = ct * 16 + (lane & 15);
        int ci = kb * 32 + ((lane >> 4) * 8) + j;
        wS[e] = f2bf(ws_[co * 128 + ci]);
        return;
    }
    idx -= 8192;
    const float* src = (idx < 36864) ? w1 : w2;
    unsigned short* dst = (idx < 36864) ? wB1 : wB2;
    int e = (idx < 36864) ? idx : idx - 36864;
    int j = e & 7, lane = (e >> 3) & 63, ct = (e >> 9) & 3, kb = e >> 11;
    int co = ct * 16 + (lane & 15);
    int k = kb * 32 + ((lane >> 4) * 8) + j;
    int ci = k & 63, tap = k >> 6;
    dst[e] = f2bf(src[(co * 64 + ci) * 9 + tap]);
}

// ---------------------------------------------------------------------------
// Stem: f1[b][p][co] = silu(bn(sum_ci x[b][ci][p] * W[co][ci]))  (NHWC bf16)
// LDS-free: each x element feeds exactly one lane of one wave, so fragments
// are built straight from global. Per (kb,t): 8 dword loads (16 consecutive
// lanes read 64B segments; t=0/1 halves share each 128B line) -> 4 cvt_pk.
// No barriers; occupancy VGPR-limited only.
__global__ __launch_bounds__(256) void stem_kernel(
    const float* __restrict__ x, const unsigned short* __restrict__ wS,
    const float* __restrict__ scale, const float* __restrict__ shift,
    unsigned short* __restrict__ f1) {
    int b = blockIdx.y;
    int tid = threadIdx.x;
    int pbase = blockIdx.x * 128;
    int lane = tid & 63, wv = tid >> 6;
    int l15 = lane & 15, q = lane >> 4;

    floatx4 acc[4][2];   // [ct][t]
    floatx4 zf = {0.0f, 0.0f, 0.0f, 0.0f};
    #pragma unroll
    for (int ct = 0; ct < 4; ++ct)
        #pragma unroll
        for (int t = 0; t < 2; ++t) acc[ct][t] = zf;

    const float* xb = x + (size_t)b * 128 * NPIX + pbase + wv * 32 + l15;

    #pragma unroll
    for (int kb = 0; kb < 4; ++kb) {
        short8 wf[4];
        #pragma unroll
        for (int ct = 0; ct < 4; ++ct)
            wf[ct] = *(const short8*)(wS + ((kb * 4 + ct) * 64 + lane) * 8);
        short8 xf[2];
        #pragma unroll
        for (int t = 0; t < 2; ++t) {
            const float* src = xb + (size_t)(kb * 32 + q * 8) * NPIX + t * 16;
            float v[8];
            #pragma unroll
            for (int j = 0; j < 8; ++j) v[j] = src[(size_t)j * NPIX];
            uint4v u;
            #pragma unroll
            for (int j = 0; j < 4; ++j) u[j] = cvt_pk_bf16(v[2 * j], v[2 * j + 1]);
            xf[t] = __builtin_bit_cast(short8, u);
        }
        #pragma unroll
        for (int ct = 0; ct < 4; ++ct)
            #pragma unroll
            for (int t = 0; t < 2; ++t)
                acc[ct][t] = __builtin_amdgcn_mfma_f32_16x16x32_bf16(
                    wf[ct], xf[t], acc[ct][t], 0, 0, 0);
    }

    float sc[4][4], sh[4][4];
    #pragma unroll
    for (int ct = 0; ct < 4; ++ct)
        #pragma unroll
        for (int r = 0; r < 4; ++r) {
            sc[ct][r] = scale[ct * 16 + q * 4 + r];
            sh[ct][r] = shift[ct * 16 + q * 4 + r];
        }

    #pragma unroll
    for (int t = 0; t < 2; ++t) {
        int pg = pbase + (wv * 2 + t) * 16 + l15;
        unsigned short* dst = f1 + ((size_t)b * NPIX + pg) * 64;
        #pragma unroll
        for (int ct = 0; ct < 4; ++ct) {
            float r0 = silu_(acc[ct][t][0] * sc[ct][0] + sh[ct][0]);
            float r1 = silu_(acc[ct][t][1] * sc[ct][1] + sh[ct][1]);
            float r2 = silu_(acc[ct][t][2] * sc[ct][2] + sh[ct][2]);
            float r3 = silu_(acc[ct][t][3] * sc[ct][3] + sh[ct][3]);
            uint2v p2 = {cvt_pk_bf16(r0, r1), cvt_pk_bf16(r2, r3)};
            *(us4*)(dst + ct * 16 + q * 4) = __builtin_bit_cast(us4, p2);
        }
    }
}

// ---------------------------------------------------------------------------
// Conv core, 4-ct N-blocking: wave wv owns output row y0+wv, all 64 co,
// 5 col-tiles. K split into 2 ci-halves; per half: stage 6x82x32ci tile
// (4 granules, 32 KB), then 9 taps. Each LDS B-read feeds 4 MFMAs.
// (R6 structure, 3 blocks/CU -- proven best; R7's single-stage DMA regressed.)
static __device__ __forceinline__ void conv_core(
    const unsigned short* __restrict__ fin, const unsigned short* __restrict__ wB,
    unsigned short* tile, floatx4 (*acc)[5], int b, int y0,
    int tid, int lane, int wv, int l15, int q) {
    const unsigned short* fb = fin + (size_t)b * NPIX * 64;
    floatx4 zf = {0.0f, 0.0f, 0.0f, 0.0f};
    #pragma unroll
    for (int c4 = 0; c4 < 4; ++c4)
        #pragma unroll
        for (int pt = 0; pt < 5; ++pt) acc[c4][pt] = zf;

    #pragma unroll
    for (int half = 0; half < 2; ++half) {
        if (half) __syncthreads();     // WAR: half-0 reads done before restage
        #pragma unroll
        for (int i = 0; i < 8; ++i) {
            int cid = i * 256 + tid;   // 1968 = 492 pix * 4 granules
            if (cid < 1968) {
                int pixL = cid >> 2, g = cid & 3;
                int r = pixL / 82, c = pixL - r * 82;
                int gy = y0 - 1 + r, gx = c - 1;
                short8 v = {};
                if ((unsigned)gy < 80u && (unsigned)gx < 80u)
                    v = *(const short8*)(
                        fb + (size_t)(gy * 80 + gx) * 64 + half * 32 + g * 8);
                *(short8*)(tile + g * CGS + pixL * 8) = v;
            }
        }
        __syncthreads();

        #pragma unroll
        for (int trow = 0; trow < 3; ++trow) {
            const int dy = trow - 1;
            #pragma unroll
            for (int tc = 0; tc < 3; ++tc) {
                const int dx = tc - 1;
                const int kb = (trow * 3 + tc) * 2 + half;
                short8 w4[4];
                #pragma unroll
                for (int c4 = 0; c4 < 4; ++c4)
                    w4[c4] = *(const short8*)(wB + ((kb * 4 + c4) * 64 + lane) * 8);
                #pragma unroll
                for (int pt = 0; pt < 5; ++pt) {
                    int pix = (wv + 1 + dy) * 82 + pt * 16 + l15 + 1 + dx;
                    short8 b8 = *(const short8*)(tile + q * CGS + pix * 8);
                    #pragma unroll
                    for (int c4 = 0; c4 < 4; ++c4)
                        acc[c4][pt] = __builtin_amdgcn_mfma_f32_16x16x32_bf16(
                            w4[c4], b8, acc[c4][pt], 0, 0, 0);
                }
            }
        }
    }
}

// ---------------------------------------------------------------------------
__global__ __launch_bounds__(256, 3) void conv3_kernel(
    const unsigned short* __restrict__ fin, const unsigned short* __restrict__ wB,
    const float* __restrict__ scale, const float* __restrict__ shift,
    unsigned short* __restrict__ fout) {
    __shared__ __align__(16) unsigned short tile[8 * CGS2];  // 41216 B
    int b = blockIdx.y, y0 = blockIdx.x * 4;
    int tid = threadIdx.x;
    int lane = tid & 63, wv = tid >> 6;
    int l15 = lane & 15, q = lane >> 4;

    floatx4 acc[4][5];
    conv_core(fin, wB, tile, acc, b, y0, tid, lane, wv, l15, q);

    float sc4[4][4], sh4[4][4];
    #pragma unroll
    for (int c4 = 0; c4 < 4; ++c4)
        #pragma unroll
        for (int r = 0; r < 4; ++r) {
            sc4[c4][r] = scale[c4 * 16 + q * 4 + r];
            sh4[c4][r] = shift[c4 * 16 + q * 4 + r];
        }
    #pragma unroll
    for (int pt = 0; pt < 5; ++pt) {
        int pg = (y0 + wv) * 80 + pt * 16 + l15;
        unsigned short* dst = fout + ((size_t)b * NPIX + pg) * 64;
        #pragma unroll
        for (int c4 = 0; c4 < 4; ++c4) {
            float r0 = silu_(acc[c4][pt][0] * sc4[c4][0] + sh4[c4][0]);
            float r1 = silu_(acc[c4][pt][1] * sc4[c4][1] + sh4[c4][1]);
            float r2 = silu_(acc[c4][pt][2] * sc4[c4][2] + sh4[c4][2]);
            float r3 = silu_(acc[c4][pt][3] * sc4[c4][3] + sh4[c4][3]);
            uint2v p2 = {cvt_pk_bf16(r0, r1), cvt_pk_bf16(r2, r3)};
            *(us4*)(dst + c4 * 16 + q * 4) = __builtin_bit_cast(us4, p2);
        }
    }
}

// ---------------------------------------------------------------------------
__global__ __launch_bounds__(256, 3) void conv_head_kernel(
    const unsigned short* __restrict__ fin, const unsigned short* __restrict__ wB,
    const float* __restrict__ scale, const float* __restrict__ shift,
    const float* __restrict__ reg_w, const float* __restrict__ reg_b,
    const float* __restrict__ obj_w, const float* __restrict__ obj_b,
    float* __restrict__ out) {
    __shared__ __align__(16) unsigned short tile[8 * CGS2];  // 41216 B
    int b = blockIdx.y, y0 = blockIdx.x * 4;
    int tid = threadIdx.x;
    int lane = tid & 63, wv = tid >> 6;
    int l15 = lane & 15, q = lane >> 4;

    floatx4 acc[4][5];
    conv_core(fin, wB, tile, acc, b, y0, tid, lane, wv, l15, q);

    __syncthreads();   // conv reads done -> reuse LDS for h (granule stride CGS2)

    // BN+SiLU -> h[granule co>>3][pix 0..319] (stride CGS2, conflict-free)
    float sc4[4][4], sh4[4][4];
    #pragma unroll
    for (int c4 = 0; c4 < 4; ++c4)
        #pragma unroll
        for (int r = 0; r < 4; ++r) {
            sc4[c4][r] = scale[c4 * 16 + q * 4 + r];
            sh4[c4][r] = shift[c4 * 16 + q * 4 + r];
        }
    #pragma unroll
    for (int pt = 0; pt < 5; ++pt) {
        int pix = wv * 80 + pt * 16 + l15;   // block-local pixel 0..319
        #pragma unroll
        for (int c4 = 0; c4 < 4; ++c4) {
            int gco = c4 * 2 + (q >> 1);     // co>>3
            float r0 = silu_(acc[c4][pt][0] * sc4[c4][0] + sh4[c4][0]);
            float r1 = silu_(acc[c4][pt][1] * sc4[c4][1] + sh4[c4][1]);
            float r2 = silu_(acc[c4][pt][2] * sc4[c4][2] + sh4[c4][2]);
            float r3 = silu_(acc[c4][pt][3] * sc4[c4][3] + sh4[c4][3]);
            uint2v p2 = {cvt_pk_bf16(r0, r1), cvt_pk_bf16(r2, r3)};
            *(us4*)(tile + gco * CGS2 + pix * 8 + (q & 1) * 4) =
                __builtin_bit_cast(us4, p2);
        }
    }

    // head B-frags: B[k=co][n] = reg_w[n][co] (n<4), obj_w[co] (n==4), else 0
    short8 hbf[2];
    #pragma unroll
    for (int kb2 = 0; kb2 < 2; ++kb2) {
        int k0 = kb2 * 32 + q * 8;
        short8 f = {};
        if (l15 < 4) {
            #pragma unroll
            for (int j = 0; j < 8; ++j) f[j] = (short)f2bf(reg_w[l15 * 64 + k0 + j]);
        } else if (l15 == 4) {
            #pragma unroll
            for (int j = 0; j < 8; ++j) f[j] = (short)f2bf(obj_w[k0 + j]);
        }
        hbf[kb2] = f;
    }

    __syncthreads();

    floatx4 zf = {0.0f, 0.0f, 0.0f, 0.0f};
    floatx4 acc5[5];
    #pragma unroll
    for (int t = 0; t < 5; ++t) acc5[t] = zf;
    #pragma unroll
    for (int t = 0; t < 5; ++t) {
        int mt = wv * 5 + t;
        int pix = mt * 16 + l15;
        #pragma unroll
        for (int kb2 = 0; kb2 < 2; ++kb2) {
            short8 a = *(const short8*)(tile + (kb2 * 4 + q) * CGS2 + pix * 8);
            acc5[t] = __builtin_amdgcn_mfma_f32_16x16x32_bf16(
                a, hbf[kb2], acc5[t], 0, 0, 0);
        }
    }

    float bias = 0.0f;
    if (l15 < 4) bias = reg_b[l15];
    else if (l15 == 4) bias = obj_b[0];

    #pragma unroll
    for (int t = 0; t < 5; ++t) {
        int mt = wv * 5 + t;
        #pragma unroll
        for (int r = 0; r < 4; ++r) {
            int pixL = mt * 16 + q * 4 + r;
            if (l15 < 5) {
                float v = acc5[t][r] + bias;
                float gx = (float)(pixL % 80);
                float gy = (float)(y0 + pixL / 80);
                float o;
                if (l15 == 0)      o = (v + gx) * 32.0f;
                else if (l15 == 1) o = (v + gy) * 32.0f;
                else if (l15 < 4)  o = __expf(v) * 32.0f;
                else               o = 1.0f / (1.0f + __expf(-v));
                out[((size_t)b * NPIX + y0 * 80 + pixL) * 5 + l15] = o;
            }
        }
    }
}

// ---------------------------------------------------------------------------
extern "C" void kernel_launch(void* const* d_in, const int* in_sizes, int n_in,
                              void* d_out, int out_size, void* d_ws, size_t ws_size,
                              hipStream_t stream) {
    const float* x          = (const float*)d_in[0];
    const float* stem_w     = (const float*)d_in[1];
    const float* stem_scale = (const float*)d_in[2];
    const float* stem_shift = (const float*)d_in[3];
    const float* c1_w       = (const float*)d_in[4];
    const float* c1_scale   = (const float*)d_in[5];
    const float* c1_shift   = (const float*)d_in[6];
    const float* c2_w       = (const float*)d_in[7];
    const float* c2_scale   = (const float*)d_in[8];
    const float* c2_shift   = (const float*)d_in[9];
    const float* reg_w      = (const float*)d_in[10];
    const float* reg_b      = (const float*)d_in[11];
    const float* obj_w      = (const float*)d_in[12];
    const float* obj_b      = (const float*)d_in[13];
    float* out = (float*)d_out;

    // ws (ushort units): wS[8192] | wB1[36864] | wB2[36864] | f1 | f2
    const size_t needed = ((size_t)8192 + 73728 + 2 * (size_t)64 * NPIX * 64) * 2;
    if (ws_size < needed) return;

    unsigned short* ws  = (unsigned short*)d_ws;
    unsigned short* wS  = ws;
    unsigned short* wB1 = ws + 8192;
    unsigned short* wB2 = wB1 + 36864;
    unsigned short* f1  = wB2 + 36864;
    unsigned short* f2  = f1 + (size_t)64 * NPIX * 64;

    rearr_w_kernel<<<320, 256, 0, stream>>>(stem_w, c1_w, c2_w, wS, wB1, wB2);
    stem_kernel<<<dim3(50, 64), 256, 0, stream>>>(x, wS, stem_scale, stem_shift, f1);
    conv3_kernel<<<dim3(20, 64), 256, 0, stream>>>(f1, wB1, c1_scale, c1_shift, f2);
    conv_head_kernel<<<dim3(20, 64), 256, 0, stream>>>(f2, wB2, c2_scale, c2_shift,
                                                       reg_w, reg_b, obj_w, obj_b, out);
}